// Round 2
// baseline (1454.939 us; speedup 1.0000x reference)
//
#include <hip/hip_runtime.h>
#include <hip/hip_bf16.h>

#define NN 100000
#define DD 64
#define NE 1600000
#define ND (NN*DD)
#define EPSLN 1e-3f

typedef __hip_bfloat16 bf16;
__device__ __forceinline__ float b2f(bf16 x){ return __bfloat162float(x); }

// ---- ws layout (floats) ----
// rs[4N]  | cA[N] | cB[N] | aggA[ND] | aggB[ND] | pf[17024] | v[128] | flag(int)
// deg/rs sublayout: [0,N) out_ab(A)  [N,2N) in_ab(B)  [2N,3N) out_ba(B)  [3N,4N) in_ba(A)
// pf sublayout: embA@0(64) embB@64(64) Wab@128(8192) bab@8320(128)
//               Wba@8448(8192) bba@16640(128) betaA@16768(128) betaB@16896(128)
#define PF_EMBA 0
#define PF_EMBB 64
#define PF_WAB  128
#define PF_BAB  8320
#define PF_WBA  8448
#define PF_BBA  16640
#define PF_BTA  16768
#define PF_BTB  16896
#define PF_TOT  17024

// 64-lane LayerNorm
__device__ __forceinline__ float wave_ln(float x, float beta){
  float s = x, s2 = x*x;
  #pragma unroll
  for (int off = 32; off >= 1; off >>= 1){
    s  += __shfl_xor(s,  off);
    s2 += __shfl_xor(s2, off);
  }
  float mu  = s  * (1.0f/DD);
  float var = s2 * (1.0f/DD) - mu*mu;
  return (x - mu) * rsqrtf(var + EPSLN) + beta;
}

// Detect input float dtype by scanning W_ab as u16. bf16-true: exponent fields
// cluster in [110,130] (W ~ 0.125*N(0,1)). f32-true: even half-words are random
// mantissa bits -> ~46% of all half-words land outside the window.
__global__ void k_detect(const unsigned short* __restrict__ w, int* __restrict__ flag){
  int lane = threadIdx.x;  // 64 threads
  int bad = 0;
  for (int i = lane; i < 4096; i += 64){   // 8KB: safe under both dtypes
    int e = (w[i] >> 7) & 0xFF;
    if (e < 110 || e > 130) bad++;
  }
  #pragma unroll
  for (int off = 32; off >= 1; off >>= 1) bad += __shfl_xor(bad, off);
  if (lane == 0) *flag = (bad > 500) ? 1 : 0;   // 1 = f32, 0 = bf16
}

// Convert all float params to f32 into pf[]
__global__ void k_convert(const void* embA, const void* embB, const void* Wab, const void* bab,
                          const void* Wba, const void* bba, const void* betaA, const void* betaB,
                          const int* __restrict__ flag, float* __restrict__ pf){
  int i = blockIdx.x*blockDim.x + threadIdx.x;
  if (i >= PF_TOT) return;
  int f32 = *flag;
  const void* src; int j;
  if      (i < PF_EMBB) { src=embA;  j=i; }
  else if (i < PF_WAB)  { src=embB;  j=i-PF_EMBB; }
  else if (i < PF_BAB)  { src=Wab;   j=i-PF_WAB; }
  else if (i < PF_WBA)  { src=bab;   j=i-PF_BAB; }
  else if (i < PF_BBA)  { src=Wba;   j=i-PF_WBA; }
  else if (i < PF_BTA)  { src=bba;   j=i-PF_BBA; }
  else if (i < PF_BTB)  { src=betaA; j=i-PF_BTA; }
  else                  { src=betaB; j=i-PF_BTB; }
  pf[i] = f32 ? ((const float*)src)[j] : b2f(((const bf16*)src)[j]);
}

__global__ void k_degree(const int* __restrict__ sab, const int* __restrict__ dab,
                         const int* __restrict__ sba, const int* __restrict__ dba,
                         float* __restrict__ deg){
  int e = blockIdx.x*blockDim.x + threadIdx.x;
  if (e >= NE) return;
  atomicAdd(&deg[sab[e]], 1.0f);
  atomicAdd(&deg[NN + dab[e]], 1.0f);
  atomicAdd(&deg[2*NN + sba[e]], 1.0f);
  atomicAdd(&deg[3*NN + dba[e]], 1.0f);
}

__global__ void k_rsqrt(float* __restrict__ deg){
  int i = blockIdx.x*blockDim.x + threadIdx.x;
  if (i >= 4*NN) return;
  deg[i] = rsqrtf(fmaxf(deg[i], 1.0f));
}

// layer-0 scalar scatter (h rows are identical -> scatter scalars, not features)
__global__ void k_l0_scatter(const int* __restrict__ sab, const int* __restrict__ dab,
                             const int* __restrict__ sba, const int* __restrict__ dba,
                             const float* __restrict__ rs,
                             float* __restrict__ cA, float* __restrict__ cB){
  int e = blockIdx.x*blockDim.x + threadIdx.x;
  if (e >= NE) return;
  atomicAdd(&cB[dab[e]], rs[sab[e]]);
  atomicAdd(&cA[dba[e]], rs[2*NN + sba[e]]);
}

// vAB = embA @ Wab[0], vBA = embB @ Wba[0]
__global__ void k_matvec(const float* __restrict__ pf, float* __restrict__ v){
  int t = threadIdx.x;           // 128 threads
  int d = t & (DD-1);
  const float* emb = pf + ((t < DD) ? PF_EMBA : PF_EMBB);
  const float* W   = pf + ((t < DD) ? PF_WAB  : PF_WBA);   // layer 0 block
  float acc = 0.f;
  for (int k = 0; k < DD; k++) acc += emb[k] * W[k*DD + d];
  v[(t < DD) ? d : (DD + d)] = acc;
}

// layer-0 node update -> h stored in d_out (A half then B half), dtype per flag
__global__ void k_layer0(const float* __restrict__ cA, const float* __restrict__ cB,
                         const float* __restrict__ rs, const float* __restrict__ v,
                         const float* __restrict__ pf, const int* __restrict__ flag,
                         void* __restrict__ out){
  int w = (blockIdx.x*blockDim.x + threadIdx.x) >> 6;
  int lane = threadIdx.x & 63;
  if (w >= 2*NN) return;
  int f32 = *flag;
  bool isA = (w < NN);
  int n = isA ? w : (w - NN);
  float c, vd, bias, beta, e0;
  if (isA){   // outA from ba relation
    c = cA[n] * rs[3*NN + n];
    vd = v[DD + lane]; bias = pf[PF_BBA + lane]; beta = pf[PF_BTA + lane]; e0 = pf[PF_EMBA + lane];
  } else {    // outB from ab relation
    c = cB[n] * rs[NN + n];
    vd = v[lane];      bias = pf[PF_BAB + lane]; beta = pf[PF_BTB + lane]; e0 = pf[PF_EMBB + lane];
  }
  float o = fmaxf(c*vd + bias, 0.f);
  float res = wave_ln(e0 + o, beta);
  size_t idx = (size_t)w*DD + lane;      // A at [0,ND), B at [ND,2ND)
  if (f32) ((float*)out)[idx] = res;
  else     ((bf16*)out)[idx] = __float2bfloat16(res);
}

// layer-1 feature scatter: one wave per edge, lane = feature; h read from d_out
__global__ void k_scatter_feat(const int* __restrict__ sab, const int* __restrict__ dab,
                               const int* __restrict__ sba, const int* __restrict__ dba,
                               const float* __restrict__ rs, const int* __restrict__ flag,
                               const void* __restrict__ hout,
                               float* __restrict__ aggA, float* __restrict__ aggB){
  long long gid = (long long)blockIdx.x*blockDim.x + threadIdx.x;
  int e = (int)(gid >> 6);
  int lane = threadIdx.x & 63;
  if (e >= 2*NE) return;
  int f32 = *flag;
  int s, d; float r; float* dst; size_t hbase;
  if (e < NE){            // aggB[dab] += hA[sab]*rs_out_ab
    s = sab[e]; d = dab[e]; r = rs[s];          dst = aggB; hbase = 0;
  } else {                // aggA[dba] += hB[sba]*rs_out_ba
    int ee = e - NE;
    s = sba[ee]; d = dba[ee]; r = rs[2*NN + s]; dst = aggA; hbase = (size_t)ND;
  }
  size_t hidx = hbase + (size_t)s*DD + lane;
  float hv = f32 ? ((const float*)hout)[hidx] : b2f(((const bf16*)hout)[hidx]);
  atomicAdd(&dst[(size_t)d*DD + lane], hv * r);
}

// layer-1 node update: out = LN(h + relu(rs_in*(agg @ W) + b), beta); h read from
// d_out and overwritten in place (same thread, read-before-write per element).
__global__ __launch_bounds__(256) void k_layer1(
    const float* __restrict__ agg, const float* __restrict__ rs_in,
    const float* __restrict__ W, const float* __restrict__ bias_,
    const float* __restrict__ beta_, const int* __restrict__ flag,
    void* __restrict__ out, size_t base){
  int lane = threadIdx.x & 63;
  int wid  = threadIdx.x >> 6;
  int wavesTotal = gridDim.x * (blockDim.x >> 6);
  int f32 = *flag;
  float Wcol[DD];
  #pragma unroll
  for (int k = 0; k < DD; k++) Wcol[k] = W[k*DD + lane];
  float bs = bias_[lane];
  float bt = beta_[lane];
  for (int n = blockIdx.x*(blockDim.x>>6) + wid; n < NN; n += wavesTotal){
    const float4* arow = (const float4*)(agg + (size_t)n*DD);
    float o = 0.f;
    #pragma unroll
    for (int k4 = 0; k4 < DD/4; k4++){
      float4 a4 = arow[k4];   // wave-uniform address -> broadcast
      o += a4.x*Wcol[4*k4] + a4.y*Wcol[4*k4+1] + a4.z*Wcol[4*k4+2] + a4.w*Wcol[4*k4+3];
    }
    o = fmaxf(o * rs_in[n] + bs, 0.f);
    size_t idx = base + (size_t)n*DD + lane;
    float hv = f32 ? ((const float*)out)[idx] : b2f(((const bf16*)out)[idx]);
    float res = wave_ln(hv + o, bt);
    if (f32) ((float*)out)[idx] = res;
    else     ((bf16*)out)[idx] = __float2bfloat16(res);
  }
}

extern "C" void kernel_launch(void* const* d_in, const int* in_sizes, int n_in,
                              void* d_out, int out_size, void* d_ws, size_t ws_size,
                              hipStream_t stream){
  const int* sab = (const int*)d_in[0];
  const int* dab = (const int*)d_in[1];
  const int* sba = (const int*)d_in[2];
  const int* dba = (const int*)d_in[3];

  float* ws   = (float*)d_ws;
  float* rs   = ws;                       // 4N
  float* cA   = ws + 4*NN;                // N
  float* cB   = ws + 5*NN;                // N
  float* aggA = ws + 6*NN;                // N*D
  float* aggB = aggA + ND;                // N*D
  float* pf   = aggB + ND;                // 17024
  float* v    = pf + PF_TOT;              // 128
  int*   flag = (int*)(v + 2*DD);         // 1

  // zero rs + c + agg (contiguous prefix)
  hipMemsetAsync(d_ws, 0, (size_t)(6*NN + 2*ND)*sizeof(float), stream);

  k_detect <<<1, 64, 0, stream>>>((const unsigned short*)d_in[6], flag);
  k_convert<<<(PF_TOT+255)/256, 256, 0, stream>>>(d_in[4], d_in[5], d_in[6], d_in[7],
                                                  d_in[8], d_in[9], d_in[10], d_in[11],
                                                  flag, pf);
  k_degree <<<(NE+255)/256, 256, 0, stream>>>(sab, dab, sba, dba, rs);
  k_rsqrt  <<<(4*NN+255)/256, 256, 0, stream>>>(rs);
  k_l0_scatter<<<(NE+255)/256, 256, 0, stream>>>(sab, dab, sba, dba, rs, cA, cB);
  k_matvec <<<1, 128, 0, stream>>>(pf, v);
  k_layer0 <<<(2*NN*64)/256, 256, 0, stream>>>(cA, cB, rs, v, pf, flag, d_out);
  k_scatter_feat<<<(2*NE*64)/256, 256, 0, stream>>>(sab, dab, sba, dba, rs, flag,
                                                    d_out, aggA, aggB);
  // A half: agg=aggA (ba), W_ba[1], b_ba[1], beta_A[1]
  k_layer1<<<1024, 256, 0, stream>>>(aggA, rs + 3*NN, pf + PF_WBA + DD*DD,
                                     pf + PF_BBA + DD, pf + PF_BTA + DD, flag, d_out, 0);
  // B half: agg=aggB (ab), W_ab[1], b_ab[1], beta_B[1]
  k_layer1<<<1024, 256, 0, stream>>>(aggB, rs + NN, pf + PF_WAB + DD*DD,
                                     pf + PF_BAB + DD, pf + PF_BTB + DD, flag, d_out, (size_t)ND);
}